// Round 1
// 297412.207 us; speedup vs baseline: 1.8507x; 1.8507x over previous
//
#include <hip/hip_runtime.h>
#include <cstdint>
#include <cstddef>

#define TT 65536
#define KK 512
#define NEGV (-10000.0f)
#define SEG 256
#define NSEG 256  // TT/SEG

typedef unsigned short u16;
typedef unsigned int   u32;
typedef unsigned long long u64;

__device__ __forceinline__ float u2f(u32 b){ union{u32 u; float f;} x; x.u=b; return x.f; }
__device__ __forceinline__ u32 f2u(float f){ union{u32 u; float f;} x; x.f=f; return x.u; }

// ---------------------------------------------------------------------------
// Per-row sort of transitions, desc by value, asc index on ties.
// svpT[k*KK + n] (rank-major, coalesced when all rows stream rank k)
// svpR[n*KK + k] (row-major, coalesced when one wave streams one row)
// ---------------------------------------------------------------------------
__global__ __launch_bounds__(512)
void sort_rows(const float* __restrict__ trans, u64* __restrict__ svpT,
               u64* __restrict__ svpR)
{
    __shared__ u64 s[KK];
    const int n = blockIdx.x, i = threadIdx.x;
    float x = trans[n*KK + i];
    u32 b = f2u(x);
    u32 ord = (b & 0x80000000u) ? ~b : (b | 0x80000000u);   // monotone u32 order
    s[i] = ((u64)(~ord) << 16) | (u32)i;                    // asc sort => value desc, p asc
    __syncthreads();
    for (int k = 2; k <= KK; k <<= 1){
        for (int j = k >> 1; j > 0; j >>= 1){
            int ixj = i ^ j;
            if (ixj > i){
                u64 a = s[i], c = s[ixj];
                bool up = ((i & k) == 0);
                if ((a > c) == up){ s[i] = c; s[ixj] = a; }
            }
            __syncthreads();
        }
    }
    u64 key = s[i];
    u32 p    = (u32)(key & 0xFFFFu);
    u32 ordv = ~(u32)(key >> 16);
    u32 bits = (ordv & 0x80000000u) ? (ordv ^ 0x80000000u) : ~ordv;
    u64 ent = ((u64)p << 32) | bits;
    svpT[(size_t)i*KK + n] = ent;   // rank-major
    svpR[(size_t)n*KK + i] = ent;   // row-major
}

// transT[p*KK + n] = trans[n*KK + p]
__global__ __launch_bounds__(512)
void transpose_k(const float* __restrict__ t, float* __restrict__ tt)
{
    const int c = blockIdx.x, r = threadIdx.x;
    tt[(size_t)c*KK + r] = t[(size_t)r*KK + c];
}

// ---------------------------------------------------------------------------
// Phase 1: sequential VALUE-ONLY scan (1 block, 512 threads; thread i = row i).
// Exact max per row per step (no argmax, no ties, no bp): publishes fv, block
// max fm, 4 fv-band compaction, REG16 + band eval with bound fl(edge+cV[15])
// <= best (value-only: <=, ties can't raise a max). Rows still unbounded get a
// WAVE-COOPERATIVE tail: whole wave scans 64 ranks/iter of svpR (coalesced),
// shfl-max reduce, exact bound fl(e3 + v_last) <= best. Stores fm per step and
// boundary states every SEG steps for the parallel backpointer pass.
// Row 1 (all-NEG): band 0 yields exactly fl(fm+NEG); bound fl((fm-0.5)+NEG)
// <= fl(fm+NEG) terminates it at band 0.
// ---------------------------------------------------------------------------
__global__ __launch_bounds__(512)
void fv_scan(const float* __restrict__ feats,
             const u64* __restrict__ svpT,
             const u64* __restrict__ svpR,
             const float* __restrict__ transT,
             float* __restrict__ fvBound,
             float* __restrict__ fmArr,
             float* __restrict__ outScore, int* __restrict__ bestOut)
{
    __shared__ float fvb[2][KK];
    __shared__ float wmaxS[2][8];
    __shared__ u64  bmS[4][8];
    __shared__ u32  cntS[4][8];
    __shared__ u64  bandE[KK + 8];
    __shared__ float rv[KK];
    __shared__ int   ri[KK];

    const int i = threadIdx.x, lane = i & 63, wv = i >> 6;
    const u64 laneLT = (1ull << lane) - 1ull;

    // top-16 (v,p) of own row in registers
    float cV[16]; int cP[16];
#pragma unroll
    for (int k = 0; k < 16; ++k){
        u64 e = svpT[(size_t)k*KK + i];
        cV[k] = u2f((u32)e); cP[k] = (int)(e >> 32);
    }

    // step 0 closed form: fv_init = [0, NEG..]; col 0 of trans == NEG exactly
    float fv_i = fmaxf(NEGV, NEGV + cV[0]) + feats[i];
    fvBound[i] = fv_i;                       // state(1) = segment-0 start
    float featCur = feats[(size_t)KK + i];

#define VMAX8(k0) { \
    float f0=fvc[cP[k0]],     f1=fvc[cP[(k0)+1]], f2=fvc[cP[(k0)+2]], f3=fvc[cP[(k0)+3]]; \
    float f4=fvc[cP[(k0)+4]], f5=fvc[cP[(k0)+5]], f6=fvc[cP[(k0)+6]], f7=fvc[cP[(k0)+7]]; \
    float m0=fmaxf(f0+cV[k0],     f1+cV[(k0)+1]), m1=fmaxf(f2+cV[(k0)+2], f3+cV[(k0)+3]); \
    float m2=fmaxf(f4+cV[(k0)+4], f5+cV[(k0)+5]), m3=fmaxf(f6+cV[(k0)+6], f7+cV[(k0)+7]); \
    best = fmaxf(best, fmaxf(fmaxf(m0,m1), fmaxf(m2,m3))); }

    for (int t = 1; t < TT; ++t){
        const int cur = t & 1;

        // ---------- publish fv ----------
        fvb[cur][i] = fv_i;
        float wm = fv_i;
#pragma unroll
        for (int o = 32; o > 0; o >>= 1) wm = fmaxf(wm, __shfl_xor(wm, o, 64));
        if (lane == 0) wmaxS[cur][wv] = wm;
        __syncthreads();                                     // A
        float fm = wmaxS[cur][0];
#pragma unroll
        for (int w = 1; w < 8; ++w) fm = fmaxf(fm, wmaxS[cur][w]);
        if (i == 0) fmArr[t] = fm;
        const float e0 = fm-0.5f, e1 = fm-1.0f, e2 = fm-1.5f, e3 = fm-2.0f;
        u64 q0 = __ballot(fv_i > e0), q1 = __ballot(fv_i > e1);
        u64 q2 = __ballot(fv_i > e2), q3 = __ballot(fv_i > e3);
        if (lane == 0){
            u64 b0 = q0, b1 = q1&~q0, b2 = q2&~q1, b3 = q3&~q2;
            bmS[0][wv]=b0; cntS[0][wv]=(u32)__builtin_popcountll(b0);
            bmS[1][wv]=b1; cntS[1][wv]=(u32)__builtin_popcountll(b1);
            bmS[2][wv]=b2; cntS[2][wv]=(u32)__builtin_popcountll(b2);
            bmS[3][wv]=b3; cntS[3][wv]=(u32)__builtin_popcountll(b3);
        }

        // ---------- overlapped: REG16 value-only (reads post-A fvb) ----------
        const float* fvc = fvb[cur];
        float featNxt = __builtin_nontemporal_load(
            &feats[(size_t)(t+1 < TT ? t+1 : t)*KK + i]);
        float best = -3.0e38f;
        VMAX8(0) VMAX8(8)
        __syncthreads();                                     // B

        // ---------- compaction ----------
        u32 tot0=0, tot1=0, tot2=0, tot3=0;
#pragma unroll
        for (int w = 0; w < 8; ++w){
            tot0 += cntS[0][w]; tot1 += cntS[1][w];
            tot2 += cntS[2][w]; tot3 += cntS[3][w];
        }
        int b_i = (fv_i > e0) ? 0 : (fv_i > e1) ? 1 : (fv_i > e2) ? 2 :
                  (fv_i > e3) ? 3 : 4;
        if (b_i < 4){
            u32 off = (b_i > 0 ? tot0 : 0u) + (b_i > 1 ? tot1 : 0u) +
                      (b_i > 2 ? tot2 : 0u);
#pragma unroll
            for (int w = 0; w < 8; ++w) off += (w < wv) ? cntS[b_i][w] : 0u;
            off += (u32)__builtin_popcountll(bmS[b_i][wv] & laneLT);
            bandE[off] = ((u64)f2u(fv_i) << 32) | (u32)i;
        }
        u32 totAll = tot0 + tot1 + tot2 + tot3;
        if (i < 8) bandE[totAll + i] = ((u64)f2u(-1.0e30f) << 32);
        int s0 = __builtin_amdgcn_readfirstlane((int)tot0);
        int s1 = __builtin_amdgcn_readfirstlane((int)tot1);
        int s2 = __builtin_amdgcn_readfirstlane((int)tot2);
        int s3 = __builtin_amdgcn_readfirstlane((int)tot3);
        __syncthreads();                                     // C

        // ---------- band eval (value-only) ----------
        bool done = false;
        int base = 0;
#pragma unroll
        for (int b = 0; b < 4; ++b){
            const int  cntb = (b==0)?s0:(b==1)?s1:(b==2)?s2:s3;
            const float edge = (b==0)?e0:(b==1)?e1:(b==2)?e2:e3;
            if (__any(!done)){
                if (!done && cntb > 0){
                    for (int u = 0; u < cntb; u += 8){
                        const int jj = base + u;
                        u64 E0=bandE[jj],   E1=bandE[jj+1], E2=bandE[jj+2], E3=bandE[jj+3];
                        u64 E4=bandE[jj+4], E5=bandE[jj+5], E6=bandE[jj+6], E7=bandE[jj+7];
                        int p0=(int)(E0&0xFFFFu), p1=(int)(E1&0xFFFFu);
                        int p2=(int)(E2&0xFFFFu), p3=(int)(E3&0xFFFFu);
                        int p4=(int)(E4&0xFFFFu), p5=(int)(E5&0xFFFFu);
                        int p6=(int)(E6&0xFFFFu), p7=(int)(E7&0xFFFFu);
                        float t0=transT[(size_t)p0*KK+i], t1=transT[(size_t)p1*KK+i];
                        float t2=transT[(size_t)p2*KK+i], t3=transT[(size_t)p3*KK+i];
                        float t4=transT[(size_t)p4*KK+i], t5=transT[(size_t)p5*KK+i];
                        float t6=transT[(size_t)p6*KK+i], t7=transT[(size_t)p7*KK+i];
                        float a0=u2f((u32)(E0>>32))+t0, a1=u2f((u32)(E1>>32))+t1;
                        float a2=u2f((u32)(E2>>32))+t2, a3=u2f((u32)(E3>>32))+t3;
                        float a4=u2f((u32)(E4>>32))+t4, a5=u2f((u32)(E5>>32))+t5;
                        float a6=u2f((u32)(E6>>32))+t6, a7=u2f((u32)(E7>>32))+t7;
                        best = fmaxf(best,
                               fmaxf(fmaxf(fmaxf(a0,a1),fmaxf(a2,a3)),
                                     fmaxf(fmaxf(a4,a5),fmaxf(a6,a7))));
                    }
                }
                done = done || (edge + cV[15] <= best);
            }
            base += cntb;
        }

        // ---------- wave-cooperative deep tail (value-only, exact) ----------
        // Pending rows = not bounded after band 3. Whole wave scans 64 ranks
        // per iteration of the row's v-sorted list (ranks >= 16); unseen p
        // have fv <= e3 (bands covered fv > e3) and v <= v_last.
        u64 pend = __ballot(!done);
        while (pend){
            int r = (int)__ffsll((unsigned long long)pend) - 1;
            pend &= pend - 1;
            const int row = (wv << 6) + r;
            float bestR = __shfl(best, r, 64);
            int rk = 16 + lane;
            for (;;){
                float vv = -1.0e30f, sc = -1.0e30f;
                if (rk < KK){
                    u64 e = svpR[(size_t)row*KK + rk];
                    vv = u2f((u32)e);
                    sc = fvc[(int)(e >> 32)] + vv;
                }
                float m = sc;
#pragma unroll
                for (int o = 32; o > 0; o >>= 1) m = fmaxf(m, __shfl_xor(m, o, 64));
                bestR = fmaxf(bestR, m);
                float vl = __shfl(vv, 63, 64);       // smallest v this chunk (OOB => -1e30 => stop)
                if (e3 + vl <= bestR) break;          // uniform break
                rk += 64;
            }
            if (lane == r) best = bestR;
        }

        // ---------- finish step ----------
        fv_i = best + featCur;
        featCur = featNxt;
        if ((t & (SEG-1)) == 0)
            fvBound[(size_t)(t >> 8)*KK + i] = fv_i;  // state(t+1), segment t/SEG start
    }
#undef VMAX8

    // ---- terminal: terminal[p] = fl(fv_T[p] + NEG); first-index argmax ----
    float tv = fv_i + NEGV;
    rv[i] = tv; ri[i] = i;
    __syncthreads();
    for (int s2 = 256; s2 > 0; s2 >>= 1){
        if (i < s2){
            float v2 = rv[i+s2]; int i2 = ri[i+s2];
            if (v2 > rv[i] || (v2 == rv[i] && i2 < ri[i])){ rv[i] = v2; ri[i] = i2; }
        }
        __syncthreads();
    }
    if (i == 0){ outScore[0] = rv[0]; *bestOut = ri[0]; }
}

// ---------------------------------------------------------------------------
// Phase 2: parallel backpointer fill. Block s re-runs segment s (SEG steps)
// from the stored boundary state (bit-exact: exact max over identical fl
// candidate values is enumeration-order independent) and computes bp[t][i]
// with reference-exact first-index-tie argmax: rank-scan svpT with strict
// bound fl(fm + v_next) < best (continue on equality => ties never skipped).
// Row 1 (all v == NEG: bound ties forever) is special-cased exactly:
// max = fl(fm+NEG) by monotonicity; argmax = first-index argmax of the
// ROUNDED fl(fv[p]+NEG), via a block reduce with min-index tie-break.
// ---------------------------------------------------------------------------
__global__ __launch_bounds__(512)
void bp_fill(const float* __restrict__ feats,
             const u64* __restrict__ svpT,
             const float* __restrict__ fvBound,
             const float* __restrict__ fmArr,
             u16* __restrict__ bp)
{
    __shared__ float fvb[2][KK];
    __shared__ u64  r1S[2][8];
    const int i = threadIdx.x, lane = i & 63, wv = i >> 6;
    const int s = blockIdx.x;
    const int t0 = s*SEG + 1;
    const int tEnd = (s == NSEG-1) ? (TT-1) : (s*SEG + SEG);

    float fv_i = fvBound[(size_t)s*KK + i];
    float featC = feats[(size_t)t0*KK + i];

#define TAKE(p_, val_) { float _val=(val_); int _p=(p_); \
    bool _tk = (_val > best) || (_val == best && _p < barg); \
    best = _tk ? _val : best; barg = _tk ? _p : barg; }

    for (int t = t0; t <= tEnd; ++t){
        const int cur = t & 1;
        fvb[cur][i] = fv_i;
        // row-1 argmax key: rounded score fl(fv+NEG), min-p tie -> max key
        float sc1 = fv_i + NEGV;
        u32 bb = f2u(sc1);
        u32 od = (bb & 0x80000000u) ? ~bb : (bb | 0x80000000u);
        u64 key = ((u64)od << 32) | (u32)(KK - 1 - i);
#pragma unroll
        for (int o = 32; o > 0; o >>= 1){
            u64 ok = __shfl_xor(key, o, 64);
            key = (ok > key) ? ok : key;
        }
        if (lane == 0) r1S[cur][wv] = key;
        float featN = (t < tEnd) ? feats[(size_t)(t+1)*KK + i] : 0.0f;
        __syncthreads();
        const float fm = fmArr[t];
        const float* fvc = fvb[cur];
        float best; int barg;
        if (i == 1){
            u64 kk = r1S[cur][0];
#pragma unroll
            for (int w = 1; w < 8; ++w){ u64 o2 = r1S[cur][w]; kk = (o2 > kk) ? o2 : kk; }
            barg = (KK - 1) - (int)(u32)kk;
            best = fm + NEGV;
        } else {
            best = -3.0e38f; barg = 0;
            for (int kb = 0; kb < KK; kb += 8){
                const u64* sp = &svpT[(size_t)kb*KK + i];
                u64 E0 = sp[0];          u64 E1 = sp[(size_t)KK];
                u64 E2 = sp[(size_t)2*KK]; u64 E3 = sp[(size_t)3*KK];
                u64 E4 = sp[(size_t)4*KK]; u64 E5 = sp[(size_t)5*KK];
                u64 E6 = sp[(size_t)6*KK]; u64 E7 = sp[(size_t)7*KK];
                int p0=(int)(E0>>32), p1=(int)(E1>>32), p2=(int)(E2>>32), p3=(int)(E3>>32);
                int p4=(int)(E4>>32), p5=(int)(E5>>32), p6=(int)(E6>>32), p7=(int)(E7>>32);
                TAKE(p0, fvc[p0] + u2f((u32)E0)); TAKE(p1, fvc[p1] + u2f((u32)E1));
                TAKE(p2, fvc[p2] + u2f((u32)E2)); TAKE(p3, fvc[p3] + u2f((u32)E3));
                TAKE(p4, fvc[p4] + u2f((u32)E4)); TAKE(p5, fvc[p5] + u2f((u32)E5));
                TAKE(p6, fvc[p6] + u2f((u32)E6)); TAKE(p7, fvc[p7] + u2f((u32)E7));
                float vlast = u2f((u32)E7);
                if (fm + vlast < best) break;   // strict: equality could tie later
            }
        }
        __builtin_nontemporal_store((u16)barg, &bp[(size_t)t*KK + i]);
        fv_i = best + featC;
        featC = featN;
    }
#undef TAKE
}

// ---------------------------------------------------------------------------
// Backtrack: segment maps (parallel) -> boundary tags -> per-segment decode.
// ---------------------------------------------------------------------------
__global__ __launch_bounds__(512)
void bt_maps(const u16* __restrict__ bp, u16* __restrict__ maps)
{
    const int s = blockIdx.x, e = threadIdx.x;
    const int tEnd = (s == NSEG-1) ? (TT-1) : (s+1)*SEG;
    const int tLow = s*SEG;
    int cur = e;
    for (int t = tEnd; t > tLow; --t) cur = (int)bp[(size_t)t*KK + cur];
    maps[s*KK + e] = (u16)cur;
}

__global__ void bt_boundaries(const u16* __restrict__ maps, const int* __restrict__ bestP,
                              int* __restrict__ btag)
{
    if (threadIdx.x != 0 || blockIdx.x != 0) return;
    int cur = *bestP;
    for (int s = NSEG-1; s >= 0; --s){
        cur = (int)maps[s*KK + cur];
        btag[s] = cur;
    }
}

__global__ void bt_decode(const u16* __restrict__ bp, const int* __restrict__ btag,
                          const int* __restrict__ bestP, float* __restrict__ outPath)
{
    const int s = blockIdx.x;
    if (threadIdx.x != 0) return;
    int tEnd, cur;
    if (s == NSEG-1){ tEnd = TT-1; cur = *bestP; outPath[TT-1] = (float)cur; }
    else            { tEnd = (s+1)*SEG; cur = btag[s+1]; }
    for (int t = tEnd; t > s*SEG; --t){
        cur = (int)bp[(size_t)t*KK + cur];
        outPath[t-1] = (float)cur;
    }
}

// ---------------------------------------------------------------------------
extern "C" void kernel_launch(void* const* d_in, const int* in_sizes, int n_in,
                              void* d_out, int out_size, void* d_ws, size_t ws_size,
                              hipStream_t stream)
{
    (void)in_sizes; (void)n_in; (void)out_size; (void)ws_size;
    const float* feats = (const float*)d_in[0];
    const float* trans = (const float*)d_in[1];
    float* out = (float*)d_out;

    char* ws = (char*)d_ws;
    size_t off = 0;
    u16*   bp     = (u16*)(ws + off);   off += (size_t)TT*KK*sizeof(u16);    // 64 MB
    u64*   svpT   = (u64*)(ws + off);   off += (size_t)KK*KK*sizeof(u64);    // 2 MB
    u64*   svpR   = (u64*)(ws + off);   off += (size_t)KK*KK*sizeof(u64);    // 2 MB
    float* transT = (float*)(ws + off); off += (size_t)KK*KK*sizeof(float);  // 1 MB
    float* fvBound= (float*)(ws + off); off += (size_t)NSEG*KK*sizeof(float);// 512 KB
    float* fmArr  = (float*)(ws + off); off += (size_t)TT*sizeof(float);     // 256 KB
    u16*   maps   = (u16*)(ws + off);   off += (size_t)NSEG*KK*sizeof(u16);  // 256 KB
    int*   btag   = (int*)(ws + off);   off += (size_t)(NSEG+8)*sizeof(int);
    int*   bestP  = (int*)(ws + off);

    hipLaunchKernelGGL(sort_rows,     dim3(KK),   dim3(512), 0, stream, trans, svpT, svpR);
    hipLaunchKernelGGL(transpose_k,   dim3(KK),   dim3(512), 0, stream, trans, transT);
    hipLaunchKernelGGL(fv_scan,       dim3(1),    dim3(512), 0, stream, feats, svpT, svpR,
                       transT, fvBound, fmArr, out, bestP);
    hipLaunchKernelGGL(bp_fill,       dim3(NSEG), dim3(512), 0, stream, feats, svpT,
                       fvBound, fmArr, bp);
    hipLaunchKernelGGL(bt_maps,       dim3(NSEG), dim3(512), 0, stream, bp, maps);
    hipLaunchKernelGGL(bt_boundaries, dim3(1),    dim3(64),  0, stream, maps, bestP, btag);
    hipLaunchKernelGGL(bt_decode,     dim3(NSEG), dim3(64),  0, stream, bp, btag, bestP, out + 1);
}